// Round 9
// baseline (482.879 us; speedup 1.0000x reference)
//
#include <hip/hip_runtime.h>
#include <hip/hip_bf16.h>
#include <stdint.h>
#include <math.h>

#define NB 16384      // batch
#define NSEQ 32       // sequence length
#define NV 1001       // vocab (V+1)
#define NROWS 32768   // 2 * NB flattened rows

// LDS h-buffer geometry (bytes): padded chunk stride kills read 4-way aliasing
#define CHK 272       // chunk stride (16 slots x 16B + 16B pad)
#define RTG (8 * CHK)     // 2176: row-tile-group stride
#define SPL (8 * RTG)     // 17408: split stride
#define HBUF (3 * SPL)    // 52224: one h buffer (3 splits)

typedef __attribute__((ext_vector_type(8))) short bf16x8;
typedef __attribute__((ext_vector_type(4))) float f32x4;

// ---------------- threefry2x32 (JAX-exact) ----------------
__device__ __forceinline__ void tf2x32(uint32_t k0, uint32_t k1,
                                       uint32_t x0, uint32_t x1,
                                       uint32_t& o0, uint32_t& o1) {
  const uint32_t ks0 = k0, ks1 = k1, ks2 = k0 ^ k1 ^ 0x1BD11BDAu;
  x0 += ks0; x1 += ks1;
  const int rA[4] = {13, 15, 26, 6};
  const int rB[4] = {17, 29, 16, 24};
#pragma unroll
  for (int i = 0; i < 4; ++i) { x0 += x1; x1 = (x1 << rA[i]) | (x1 >> (32 - rA[i])); x1 ^= x0; }
  x0 += ks1; x1 += ks2 + 1u;
#pragma unroll
  for (int i = 0; i < 4; ++i) { x0 += x1; x1 = (x1 << rB[i]) | (x1 >> (32 - rB[i])); x1 ^= x0; }
  x0 += ks2; x1 += ks0 + 2u;
#pragma unroll
  for (int i = 0; i < 4; ++i) { x0 += x1; x1 = (x1 << rA[i]) | (x1 >> (32 - rA[i])); x1 ^= x0; }
  x0 += ks0; x1 += ks1 + 3u;
#pragma unroll
  for (int i = 0; i < 4; ++i) { x0 += x1; x1 = (x1 << rB[i]) | (x1 >> (32 - rB[i])); x1 ^= x0; }
  x0 += ks1; x1 += ks2 + 4u;
#pragma unroll
  for (int i = 0; i < 4; ++i) { x0 += x1; x1 = (x1 << rA[i]) | (x1 >> (32 - rA[i])); x1 ^= x0; }
  o0 = x0 + ks2; o1 = x1 + ks0 + 5u;
}

__device__ __forceinline__ float gumbel_from_bits(uint32_t bits) {
  uint32_t fb = (bits >> 9) | 0x3f800000u;
  float u = __uint_as_float(fb) - 1.0f;
  u = fmaxf(u, 1.17549435e-38f);
  return -logf(-logf(u));
}

__device__ __forceinline__ float sigm(float x) { return 1.0f / (1.0f + __expf(-x)); }
__device__ __forceinline__ float tanh_(float x) {
  float e = __expf(2.0f * x);
  return 1.0f - 2.0f / (e + 1.0f);
}

__device__ __forceinline__ float dot64(const float* __restrict__ w, const float* h) {
  float a = 0.f;
#pragma unroll
  for (int k = 0; k < 64; ++k) a = fmaf(w[k], h[k], a);
  return a;
}

// round-to-bf16 (RNE): returns bits, outputs rounded-back float
__device__ __forceinline__ unsigned short bfbits(float x, float& xf) {
  __hip_bfloat16 hb = __float2bfloat16(x);
  xf = __bfloat162float(hb);
  unsigned short u;
  __builtin_memcpy(&u, &hb, 2);
  return u;
}

// Team-of-4 categorical sample + logprob (bit-exact since r3 — do not touch)
template <int N>
__device__ __forceinline__ void samp_team(const float* lg, int g, int C,
                                          uint32_t k0, uint32_t k1, int b,
                                          int& sOut, float& lpOut) {
  float m = -__builtin_inff();
#pragma unroll
  for (int i = 0; i < N; ++i) m = fmaxf(m, lg[i]);
  m = fmaxf(m, __shfl_xor(m, 1));
  m = fmaxf(m, __shfl_xor(m, 2));
  float se = 0.f;
#pragma unroll
  for (int i = 0; i < N; ++i) se += expf(lg[i] - m);
  se += __shfl_xor(se, 1);
  se += __shfl_xor(se, 2);
  const float lse = logf(se);
  float bz = -__builtin_inff(), bl = 0.f;
  int bi = 0x7fffffff;
#pragma unroll
  for (int i = 0; i < N; ++i) {
    const int c = g + 4 * i;
    uint32_t o0, o1; tf2x32(k0, k1, 0u, (uint32_t)(b * C + c), o0, o1);
    const float z = lg[i] + gumbel_from_bits(o0 ^ o1);
    if (z > bz || (z == bz && c < bi)) { bz = z; bi = c; bl = lg[i]; }
  }
#pragma unroll
  for (int d = 1; d <= 2; d <<= 1) {
    const float z2 = __shfl_xor(bz, d);
    const int i2 = __shfl_xor(bi, d);
    const float l2 = __shfl_xor(bl, d);
    if (z2 > bz || (z2 == bz && i2 < bi)) { bz = z2; bi = i2; bl = l2; }
  }
  sOut = bi;
  lpOut = (bl - m) - lse;
}

// ---------------- kernel A: packed precompute ----------------
// Gate-interleaved j' = unit*4 + gate (gate order i,f,g,o; torch j = gate*64+unit)
// embedWi[v][j'] = b_ih[j] + b_hh[j] + sum_k embed[v][k]*W_ih[j][k]   (fp32)
// Wsp[(s*256 + j')*64 + m]: m = kc*32 + q*8 + p holds split_s(W[j][k]) with
//   k = kc*32 + q*8 + cmap(p), cmap(p) = (p>>1) + ((p&1)<<2).
// Same permutation applied to B-writes in k_lstm -> MFMA dot product unchanged,
// but h-writes of jt-even/odd pairs land in ONE dword (merged b32, 2-way banks).
__global__ __launch_bounds__(256) void k_prep(
    const float* __restrict__ embed, const float* __restrict__ W_ih,
    const float* __restrict__ W_hh, const float* __restrict__ b_ih,
    const float* __restrict__ b_hh, float* __restrict__ embedWi,
    unsigned short* __restrict__ Wsp) {
  if (blockIdx.x >= NV) {
    int idx = (blockIdx.x - NV) * 256 + threadIdx.x;  // 0..49151
    int s = idx >> 14;
    int rem = idx & 16383;
    int jp = rem >> 6, m = rem & 63;
    int kc = m >> 5, q = (m >> 3) & 3, p = m & 7;
    int k = kc * 32 + q * 8 + ((p >> 1) + ((p & 1) << 2));
    int j = (jp & 3) * 64 + (jp >> 2);
    float w = W_hh[j * 64 + k];
    float f1, f2, f3;
    unsigned short b1 = bfbits(w, f1);
    unsigned short b2 = bfbits(w - f1, f2);
    unsigned short b3 = bfbits(w - f1 - f2, f3);
    Wsp[idx] = (s == 0) ? b1 : (s == 1) ? b2 : b3;
    return;
  }
  __shared__ float er[64];
  int v = blockIdx.x;
  if (threadIdx.x < 64) er[threadIdx.x] = embed[v * 64 + threadIdx.x];
  __syncthreads();
  int jp = threadIdx.x;
  int j = (jp & 3) * 64 + (jp >> 2);
  float a = b_ih[j] + b_hh[j];
#pragma unroll
  for (int k = 0; k < 64; ++k) a = fmaf(W_ih[j * 64 + k], er[k], a);
  embedWi[v * 256 + jp] = a;
}

// ---------------- kernel B: LSTM via MFMA, pinned A-frags ----------
// r8 structure + two fixes:
// (1) A-frags pinned in VGPRs via asm "+v" — r8's VGPR=128 shows the compiler
//     rematerialized them from global each step (vmcnt stalls inside the MFMA
//     stream = the 2-3x slack). Budget at (512,2) is 256 VGPR/wave.
// (2) permuted k-order + merged b32 h-writes (bank-2-way) + 272B chunk pad
//     (reader quads spread) — kills the 6.3M conflict cycles.
__global__ __launch_bounds__(512, 2) void k_lstm(
    const int* __restrict__ inst0, const int* __restrict__ inst1,
    const float* __restrict__ embedWi, const unsigned short* __restrict__ Wsp,
    float* __restrict__ hT) {
  extern __shared__ char smc[];
  int* idsb = (int*)(smc + 2 * HBUF);

  const int tid = threadIdx.x;
  const int lane = tid & 63;
  const int wave = tid >> 6;      // 0..7
  const int wgj = wave >> 1;      // j'-quarter
  const int wrh = wave & 1;       // row half
  const int n15 = lane & 15;
  const int quad = lane >> 4;
  const int blk = blockIdx.x;
  const int rowbase = blk * 128;
  const int rb = rowbase & (NB - 1);
  const int* __restrict__ inst = (blk < 128) ? inst0 : inst1;

  // static A-frags: afr[jt][kc][s], element p = W_s[j'][kc*32+quad*8+cmap(p)]
  bf16x8 afr[4][2][3];
#pragma unroll
  for (int jt = 0; jt < 4; ++jt) {
    const int jrow = (wgj * 4 + jt) * 16 + n15;
#pragma unroll
    for (int kc = 0; kc < 2; ++kc)
#pragma unroll
      for (int s = 0; s < 3; ++s)
        afr[jt][kc][s] =
            *(const bf16x8*)(Wsp + ((s * 256 + jrow) * 64 + kc * 32 + quad * 8));
  }
  // pin: forbid rematerialization (value marked asm-modified)
#pragma unroll
  for (int jt = 0; jt < 4; ++jt)
#pragma unroll
    for (int kc = 0; kc < 2; ++kc)
#pragma unroll
      for (int s = 0; s < 3; ++s)
        asm volatile("" : "+v"(afr[jt][kc][s]));

  for (int i = tid; i < HBUF / 4; i += 512) ((float*)smc)[i] = 0.f;  // zero buf 0
  if (tid < 128) idsb[tid] = inst[(rb + tid) * NSEQ];

  float cst[16];
#pragma unroll
  for (int i = 0; i < 16; ++i) cst[i] = 0.f;

  __syncthreads();

#pragma unroll 1
  for (int t = 0; t < NSEQ; ++t) {
    const char* __restrict__ hbr = smc + (t & 1) * HBUF;
    char* __restrict__ hbw = smc + ((t & 1) ^ 1) * HBUF;

    int vv[4];
#pragma unroll
    for (int rt = 0; rt < 4; ++rt)
      vv[rt] = idsb[(t & 1) * 128 + wrh * 64 + rt * 16 + n15];
    if (tid < 128 && t + 1 < NSEQ)
      idsb[((t + 1) & 1) * 128 + tid] = inst[(rb + tid) * NSEQ + t + 1];

    f32x4 C[4][4];
#pragma unroll
    for (int jt = 0; jt < 4; ++jt)
#pragma unroll
      for (int rt = 0; rt < 4; ++rt) C[jt][rt] = (f32x4){0.f, 0.f, 0.f, 0.f};

#pragma unroll
    for (int rt = 0; rt < 4; ++rt) {
      const int rtg = wrh * 4 + rt;
      bf16x8 bfr[2][3];
#pragma unroll
      for (int kc = 0; kc < 2; ++kc)
#pragma unroll
        for (int s = 0; s < 3; ++s)
          bfr[kc][s] = *(const bf16x8*)(hbr + s * SPL + rtg * RTG +
                                        (kc * 4 + quad) * CHK + n15 * 16);
#pragma unroll
      for (int jt = 0; jt < 4; ++jt) {
#pragma unroll
        for (int kc = 0; kc < 2; ++kc) {
          f32x4 acc = C[jt][rt];
          acc = __builtin_amdgcn_mfma_f32_16x16x32_bf16(afr[jt][kc][1], bfr[kc][2], acc, 0, 0, 0);
          acc = __builtin_amdgcn_mfma_f32_16x16x32_bf16(afr[jt][kc][2], bfr[kc][1], acc, 0, 0, 0);
          acc = __builtin_amdgcn_mfma_f32_16x16x32_bf16(afr[jt][kc][0], bfr[kc][2], acc, 0, 0, 0);
          acc = __builtin_amdgcn_mfma_f32_16x16x32_bf16(afr[jt][kc][2], bfr[kc][0], acc, 0, 0, 0);
          acc = __builtin_amdgcn_mfma_f32_16x16x32_bf16(afr[jt][kc][1], bfr[kc][1], acc, 0, 0, 0);
          acc = __builtin_amdgcn_mfma_f32_16x16x32_bf16(afr[jt][kc][0], bfr[kc][1], acc, 0, 0, 0);
          acc = __builtin_amdgcn_mfma_f32_16x16x32_bf16(afr[jt][kc][1], bfr[kc][0], acc, 0, 0, 0);
          acc = __builtin_amdgcn_mfma_f32_16x16x32_bf16(afr[jt][kc][0], bfr[kc][0], acc, 0, 0, 0);
          C[jt][rt] = acc;
        }
      }
    }

    // epilogue: rt-major, es ping-pong; merged b32 split-writes
    const bool last = (t == NSEQ - 1);
    float4 esA[4], esB[4];
#pragma unroll
    for (int jt = 0; jt < 4; ++jt)
      esA[jt] = *(const float4*)(embedWi + vv[0] * 256 + (wgj * 16 + jt * 4 + quad) * 4);
#pragma unroll
    for (int rt = 0; rt < 4; ++rt) {
      if (rt < 3) {
#pragma unroll
        for (int jt = 0; jt < 4; ++jt)
          esB[jt] = *(const float4*)(embedWi + vv[rt + 1] * 256 +
                                     (wgj * 16 + jt * 4 + quad) * 4);
      }
      const int r = wrh * 64 + rt * 16 + n15;
      const int rtg = wrh * 4 + rt;
      float hval[4];
      unsigned short s1[4], s2[4], s3[4];
#pragma unroll
      for (int jt = 0; jt < 4; ++jt) {
        const float gi = C[jt][rt].x + esA[jt].x;
        const float gf = C[jt][rt].y + esA[jt].y;
        const float gg = C[jt][rt].z + esA[jt].z;
        const float go = C[jt][rt].w + esA[jt].w;
        const float ci = sigm(gf) * cst[jt * 4 + rt] + sigm(gi) * tanh_(gg);
        cst[jt * 4 + rt] = ci;
        const float h = sigm(go) * tanh_(ci);
        hval[jt] = h;
        float f1, f2, f3;
        s1[jt] = bfbits(h, f1);
        s2[jt] = bfbits(h - f1, f2);
        s3[jt] = bfbits(h - f1 - f2, f3);
      }
      char* base = hbw + rtg * RTG + n15 * 16 + quad * 4;
      *(uint32_t*)(base + 0 * SPL + (wgj * 2 + 0) * CHK) = (uint32_t)s1[0] | ((uint32_t)s1[1] << 16);
      *(uint32_t*)(base + 0 * SPL + (wgj * 2 + 1) * CHK) = (uint32_t)s1[2] | ((uint32_t)s1[3] << 16);
      *(uint32_t*)(base + 1 * SPL + (wgj * 2 + 0) * CHK) = (uint32_t)s2[0] | ((uint32_t)s2[1] << 16);
      *(uint32_t*)(base + 1 * SPL + (wgj * 2 + 1) * CHK) = (uint32_t)s2[2] | ((uint32_t)s2[3] << 16);
      *(uint32_t*)(base + 2 * SPL + (wgj * 2 + 0) * CHK) = (uint32_t)s3[0] | ((uint32_t)s3[1] << 16);
      *(uint32_t*)(base + 2 * SPL + (wgj * 2 + 1) * CHK) = (uint32_t)s3[2] | ((uint32_t)s3[3] << 16);
      if (last) {
#pragma unroll
        for (int jt = 0; jt < 4; ++jt)
          hT[(wgj * 16 + jt * 4 + quad) * NROWS + rowbase + r] = hval[jt];
      }
#pragma unroll
      for (int jt = 0; jt < 4; ++jt) esA[jt] = esB[jt];
    }
    __syncthreads();
  }
}

// ---------------- kernel C: heads, 4-lane team per row (bit-exact r3+) -----
__global__ __launch_bounds__(256) void k_heads(
    const int* __restrict__ canvas0, const int* __restrict__ canvas1,
    const int* __restrict__ ref,
    const float* __restrict__ Wc, const float* __restrict__ bc,
    const float* __restrict__ Ws, const float* __restrict__ bs,
    const float* __restrict__ Wl, const float* __restrict__ bl,
    const float* __restrict__ Wr1, const float* __restrict__ br1,
    const float* __restrict__ Wr2, const float* __restrict__ br2,
    const float* __restrict__ Wp, const float* __restrict__ bp,
    const float* __restrict__ hT, float* __restrict__ out) {
  const int tid = threadIdx.x;
  const int g = tid & 3;
  const int s = blockIdx.x & 1;
  const int b = (blockIdx.x >> 1) * 64 + (tid >> 2);
  const float NEG = -__builtin_inff();

  uint32_t kk0[7], kk1[7];
#pragma unroll
  for (int i = 0; i < 7; ++i) {
    uint32_t o0, o1; tf2x32(0u, 42u, 0u, (uint32_t)i, o0, o1);
    kk0[i] = o0; kk1[i] = o1;
  }

  float h[64];
#pragma unroll
  for (int u = 0; u < 64; ++u) h[u] = hT[u * NROWS + s * NB + b];

  float lgc[1], lgs[1];
  lgc[0] = (g < 3) ? (bc[g] + dot64(Wc + g * 64, h)) : NEG;
  lgs[0] = (g < 3) ? (bs[g] + dot64(Ws + g * 64, h)) : NEG;

  if (s == 0) {
    int cs0, ss0, loc0; float clp0, slp0, llp0;
    samp_team<1>(lgc, g, 3, kk0[0], kk1[0], b, cs0, clp0);
    samp_team<1>(lgs, g, 3, kk0[1], kk1[1], b, ss0, slp0);
    float lgl[7];
#pragma unroll
    for (int i = 0; i < 7; ++i) {
      const int cc = g + 4 * i;
      lgl[i] = (cc < 25) ? (bl[cc] + dot64(Wl + cc * 64, h)) : NEG;
    }
    samp_team<7>(lgl, g, 25, kk0[2], kk1[2], b, loc0, llp0);

    if (g == 0) {
      const int p0 = min(max(loc0, 0), 24);
      const int4 pt = ((const int4*)(canvas1 + b * 100))[p0];
      const bool ok0 = (loc0 >= 0) && (loc0 < 25) && (pt.x + pt.y + pt.z + pt.w >= 0);
      const float loc_r0 = ok0 ? 1.f : -1.f;
      const float col_r0 = ok0 ? ((cs0 == pt.x) ? 1.f : -1.f) : 0.f;
      out[0 * NB + b] = clp0;
      out[1 * NB + b] = slp0;
      out[2 * NB + b] = llp0;
      out[7 * NB + b] = loc_r0;
      out[8 * NB + b] = col_r0;
      out[9 * NB + b] = loc_r0;
    }
  } else {
    int cs1, ss1, ls1; float clp1, slp1, llp1;
    samp_team<1>(lgc, g, 3, kk0[3], kk1[3], b, cs1, clp1);
    samp_team<1>(lgs, g, 3, kk0[4], kk1[4], b, ss1, slp1);
    float lgp[2];
#pragma unroll
    for (int i = 0; i < 2; ++i) {
      const int cc = g + 4 * i;
      lgp[i] = bp[cc] + dot64(Wp + cc * 64, h);
    }
    samp_team<2>(lgp, g, 8, kk0[5], kk1[5], b, ls1, llp1);

    float uv8[8], w64[8], w65[8], w66[8], w67[8], wr2[8];
#pragma unroll
    for (int i = 0; i < 8; ++i) {
      const int j = g + 4 * i;
      uv8[i] = br1[j] + dot64(Wr1 + j * 68, h);
      const float* wr = Wr1 + j * 68 + 64;
      w64[i] = wr[0]; w65[i] = wr[1]; w66[i] = wr[2]; w67[i] = wr[3];
      wr2[i] = Wr2[j];
    }
    float lgA[7];
#pragma unroll
    for (int i = 0; i < 7; ++i) lgA[i] = NEG;
    const float b2 = br2[0];
#pragma unroll
    for (int p = 0; p < 25; ++p) {
      const int4 c4 = ((const int4*)(canvas0 + b * 100))[p];
      const float f0 = (float)c4.x, f1 = (float)c4.y;
      const float f2 = (float)c4.z, f3 = (float)c4.w;
      float part = 0.f;
#pragma unroll
      for (int i = 0; i < 8; ++i) {
        float hj = uv8[i];
        hj = fmaf(w64[i], f0, hj);
        hj = fmaf(w65[i], f1, hj);
        hj = fmaf(w66[i], f2, hj);
        hj = fmaf(w67[i], f3, hj);
        part = fmaf(wr2[i], fmaxf(hj, 0.f), part);
      }
      part += __shfl_xor(part, 1);
      part += __shfl_xor(part, 2);
      const float ap = b2 + part;
      if ((p & 3) == g) lgA[p >> 2] = ap;
    }
    int att_s; float alp1;
    samp_team<7>(lgA, g, 25, kk0[6], kk1[6], b, att_s, alp1);

    if (g == 0) {
      const int4 r4 = ((const int4*)(canvas0 + b * 100))[att_s];
      const int4 rr = *(const int4*)(ref + b * 4);
      const bool match = (r4.x == rr.x) && (r4.y == rr.y) &&
                         (r4.z == rr.z) && (r4.w == rr.w);
      const float att_reward = match ? 1.f : -1.f;
      const int ox = (int)((0x22001120u >> (ls1 * 4)) & 0xFu) - 1;
      const int oy = (int)((0x20200211u >> (ls1 * 4)) & 0xFu) - 1;
      const int loc1 = (r4.z + ox) * 5 + (r4.w + oy);
      const int p1 = min(max(loc1, 0), 24);
      const int4 q4 = ((const int4*)(canvas1 + b * 100))[p1];
      const bool ok1 = (loc1 >= 0) && (loc1 < 25) && (q4.x + q4.y + q4.z + q4.w >= 0);
      const float loc_r1 = ok1 ? 1.f : -1.f;
      const float col_r1 = ok1 ? ((cs1 == q4.x) ? 1.f : -1.f) : 0.f;
      out[3 * NB + b]  = clp1;
      out[4 * NB + b]  = slp1;
      out[5 * NB + b]  = llp1;
      out[6 * NB + b]  = alp1;
      out[10 * NB + b] = loc_r1;
      out[11 * NB + b] = col_r1;
      out[12 * NB + b] = loc_r1;
      out[13 * NB + b] = att_reward;
    }
  }
}

extern "C" void kernel_launch(void* const* d_in, const int* in_sizes, int n_in,
                              void* d_out, int out_size, void* d_ws, size_t ws_size,
                              hipStream_t stream) {
  const int* inst0 = (const int*)d_in[0];
  const int* inst1 = (const int*)d_in[1];
  const int* canvas0 = (const int*)d_in[2];
  const int* canvas1 = (const int*)d_in[3];
  const int* ref = (const int*)d_in[4];
  const float* embed = (const float*)d_in[5];
  const float* W_ih = (const float*)d_in[6];
  const float* W_hh = (const float*)d_in[7];
  const float* b_ih = (const float*)d_in[8];
  const float* b_hh = (const float*)d_in[9];
  const float* Wc = (const float*)d_in[10];
  const float* bc = (const float*)d_in[11];
  const float* Ws = (const float*)d_in[12];
  const float* bs = (const float*)d_in[13];
  const float* Wl = (const float*)d_in[14];
  const float* bl = (const float*)d_in[15];
  const float* Wr1 = (const float*)d_in[16];
  const float* br1 = (const float*)d_in[17];
  const float* Wr2 = (const float*)d_in[18];
  const float* br2 = (const float*)d_in[19];
  const float* Wp = (const float*)d_in[20];
  const float* bp = (const float*)d_in[21];

  float* ws = (float*)d_ws;
  float* embedWi = ws;                               // 1001*256 fp32
  unsigned short* Wsp = (unsigned short*)(ws + NV * 256);  // 3*256*64 bf16
  float* hT = ws + NV * 256 + 24576;                 // 64*32768 fp32
  float* out = (float*)d_out;

  (void)hipFuncSetAttribute((const void*)k_lstm,
                            hipFuncAttributeMaxDynamicSharedMemorySize, 163840);

  const size_t ldsBytes = 2 * HBUF + 1024;  // h dbuf (104448) + ids
  k_prep<<<NV + 192, 256, 0, stream>>>(embed, W_ih, W_hh, b_ih, b_hh, embedWi, Wsp);
  k_lstm<<<256, 512, ldsBytes, stream>>>(inst0, inst1, embedWi, Wsp, hT);
  k_heads<<<512, 256, 0, stream>>>(canvas0, canvas1, ref, Wc, bc, Ws, bs,
                                   Wl, bl, Wr1, br1, Wr2, br2, Wp, bp, hT, out);
}

// Round 10
// 428.279 us; speedup vs baseline: 1.1275x; 1.1275x over previous
//
#include <hip/hip_runtime.h>
#include <hip/hip_bf16.h>
#include <stdint.h>
#include <math.h>

#define NB 16384      // batch
#define NSEQ 32       // sequence length
#define NV 1001       // vocab (V+1)
#define NROWS 32768   // 2 * NB flattened rows

// LDS h-buffer geometry (bytes), R=64 rows per WG
#define CHK 272           // chunk stride (16 rows x 16B + 16B pad)
#define RTG (8 * CHK)     // 2176: row-tile-group stride (8 k-chunks)
#define SPL (4 * RTG)     // 8704: split stride (4 row-tile-groups)
#define HBUF (3 * SPL)    // 26112: one h buffer (3 splits)

typedef __attribute__((ext_vector_type(8))) short bf16x8;
typedef __attribute__((ext_vector_type(4))) float f32x4;

// ---------------- threefry2x32 (JAX-exact) ----------------
__device__ __forceinline__ void tf2x32(uint32_t k0, uint32_t k1,
                                       uint32_t x0, uint32_t x1,
                                       uint32_t& o0, uint32_t& o1) {
  const uint32_t ks0 = k0, ks1 = k1, ks2 = k0 ^ k1 ^ 0x1BD11BDAu;
  x0 += ks0; x1 += ks1;
  const int rA[4] = {13, 15, 26, 6};
  const int rB[4] = {17, 29, 16, 24};
#pragma unroll
  for (int i = 0; i < 4; ++i) { x0 += x1; x1 = (x1 << rA[i]) | (x1 >> (32 - rA[i])); x1 ^= x0; }
  x0 += ks1; x1 += ks2 + 1u;
#pragma unroll
  for (int i = 0; i < 4; ++i) { x0 += x1; x1 = (x1 << rB[i]) | (x1 >> (32 - rB[i])); x1 ^= x0; }
  x0 += ks2; x1 += ks0 + 2u;
#pragma unroll
  for (int i = 0; i < 4; ++i) { x0 += x1; x1 = (x1 << rA[i]) | (x1 >> (32 - rA[i])); x1 ^= x0; }
  x0 += ks0; x1 += ks1 + 3u;
#pragma unroll
  for (int i = 0; i < 4; ++i) { x0 += x1; x1 = (x1 << rB[i]) | (x1 >> (32 - rB[i])); x1 ^= x0; }
  x0 += ks1; x1 += ks2 + 4u;
#pragma unroll
  for (int i = 0; i < 4; ++i) { x0 += x1; x1 = (x1 << rA[i]) | (x1 >> (32 - rA[i])); x1 ^= x0; }
  o0 = x0 + ks2; o1 = x1 + ks0 + 5u;
}

__device__ __forceinline__ float gumbel_from_bits(uint32_t bits) {
  uint32_t fb = (bits >> 9) | 0x3f800000u;
  float u = __uint_as_float(fb) - 1.0f;
  u = fmaxf(u, 1.17549435e-38f);
  return -logf(-logf(u));
}

__device__ __forceinline__ float sigm(float x) { return 1.0f / (1.0f + __expf(-x)); }
__device__ __forceinline__ float tanh_(float x) {
  float e = __expf(2.0f * x);
  return 1.0f - 2.0f / (e + 1.0f);
}

__device__ __forceinline__ float dot64(const float* __restrict__ w, const float* h) {
  float a = 0.f;
#pragma unroll
  for (int k = 0; k < 64; ++k) a = fmaf(w[k], h[k], a);
  return a;
}

// round-to-bf16 (RNE): returns bits, outputs rounded-back float
__device__ __forceinline__ unsigned short bfbits(float x, float& xf) {
  __hip_bfloat16 hb = __float2bfloat16(x);
  xf = __bfloat162float(hb);
  unsigned short u;
  __builtin_memcpy(&u, &hb, 2);
  return u;
}

// Team-of-4 categorical sample + logprob (bit-exact since r3 — do not touch)
template <int N>
__device__ __forceinline__ void samp_team(const float* lg, int g, int C,
                                          uint32_t k0, uint32_t k1, int b,
                                          int& sOut, float& lpOut) {
  float m = -__builtin_inff();
#pragma unroll
  for (int i = 0; i < N; ++i) m = fmaxf(m, lg[i]);
  m = fmaxf(m, __shfl_xor(m, 1));
  m = fmaxf(m, __shfl_xor(m, 2));
  float se = 0.f;
#pragma unroll
  for (int i = 0; i < N; ++i) se += expf(lg[i] - m);
  se += __shfl_xor(se, 1);
  se += __shfl_xor(se, 2);
  const float lse = logf(se);
  float bz = -__builtin_inff(), bl = 0.f;
  int bi = 0x7fffffff;
#pragma unroll
  for (int i = 0; i < N; ++i) {
    const int c = g + 4 * i;
    uint32_t o0, o1; tf2x32(k0, k1, 0u, (uint32_t)(b * C + c), o0, o1);
    const float z = lg[i] + gumbel_from_bits(o0 ^ o1);
    if (z > bz || (z == bz && c < bi)) { bz = z; bi = c; bl = lg[i]; }
  }
#pragma unroll
  for (int d = 1; d <= 2; d <<= 1) {
    const float z2 = __shfl_xor(bz, d);
    const int i2 = __shfl_xor(bi, d);
    const float l2 = __shfl_xor(bl, d);
    if (z2 > bz || (z2 == bz && i2 < bi)) { bz = z2; bi = i2; bl = l2; }
  }
  sOut = bi;
  lpOut = (bl - m) - lse;
}

// ---------------- kernel A: packed precompute (identical to r9) ------------
// Gate-interleaved j' = unit*4 + gate (gate order i,f,g,o; torch j = gate*64+unit)
// embedWi[v][j'] = b_ih[j] + b_hh[j] + sum_k embed[v][k]*W_ih[j][k]   (fp32)
// Wsp[(s*256 + j')*64 + m]: m = kc*32 + q*8 + p holds split_s(W[j][k]) with
//   k = kc*32 + q*8 + cmap(p), cmap(p) = (p>>1) + ((p&1)<<2).
__global__ __launch_bounds__(256) void k_prep(
    const float* __restrict__ embed, const float* __restrict__ W_ih,
    const float* __restrict__ W_hh, const float* __restrict__ b_ih,
    const float* __restrict__ b_hh, float* __restrict__ embedWi,
    unsigned short* __restrict__ Wsp) {
  if (blockIdx.x >= NV) {
    int idx = (blockIdx.x - NV) * 256 + threadIdx.x;  // 0..49151
    int s = idx >> 14;
    int rem = idx & 16383;
    int jp = rem >> 6, m = rem & 63;
    int kc = m >> 5, q = (m >> 3) & 3, p = m & 7;
    int k = kc * 32 + q * 8 + ((p >> 1) + ((p & 1) << 2));
    int j = (jp & 3) * 64 + (jp >> 2);
    float w = W_hh[j * 64 + k];
    float f1, f2, f3;
    unsigned short b1 = bfbits(w, f1);
    unsigned short b2 = bfbits(w - f1, f2);
    unsigned short b3 = bfbits(w - f1 - f2, f3);
    Wsp[idx] = (s == 0) ? b1 : (s == 1) ? b2 : b3;
    return;
  }
  __shared__ float er[64];
  int v = blockIdx.x;
  if (threadIdx.x < 64) er[threadIdx.x] = embed[v * 64 + threadIdx.x];
  __syncthreads();
  int jp = threadIdx.x;
  int j = (jp & 3) * 64 + (jp >> 2);
  float a = b_ih[j] + b_hh[j];
#pragma unroll
  for (int k = 0; k < 64; ++k) a = fmaf(W_ih[j * 64 + k], er[k], a);
  embedWi[v * 256 + jp] = a;
}

// ---------------- kernel B: LSTM via MFMA, honest-128-reg tile -------------
// 512 WGs x 512 thr; WG = 64 rows x 256 j' (2 WGs/CU -> 4 waves/SIMD, the
// binary occupancy tier r8/r9 missed: their live set ~180 forced silent remat
// at the 128 cap). Wave = j'-eighth (2 j-tiles) x all 64 rows (4 r-tiles).
// afr = 2jt x 2kc x 3s = 48 VGPR; per-rt pipelining (MFMA -> epilogue ->
// h-writes; legal under double-buffered h) keeps C alive = 8 regs.
// 6 products (drop w2h3, w3h2, w3h3 — all <= 2^-24 rel, fp32-reorder class).
__global__ __launch_bounds__(512, 4) void k_lstm(
    const int* __restrict__ inst0, const int* __restrict__ inst1,
    const float* __restrict__ embedWi, const unsigned short* __restrict__ Wsp,
    float* __restrict__ hT) {
  extern __shared__ char smc[];
  int* idsb = (int*)(smc + 2 * HBUF);

  const int tid = threadIdx.x;
  const int lane = tid & 63;
  const int e8 = tid >> 6;        // wave = j'-eighth 0..7
  const int n15 = lane & 15;
  const int quad = lane >> 4;
  const int blk = blockIdx.x;     // 0..511
  const int rowbase = blk * 64;   // flat row base
  const int rb = (blk & 255) * 64;
  const int* __restrict__ inst = (blk < 256) ? inst0 : inst1;

  // static A-frags: afr[jt][kc][s]; element p = W_s[j'][kc*32+quad*8+cmap(p)]
  bf16x8 afr[2][2][3];
#pragma unroll
  for (int jt = 0; jt < 2; ++jt) {
    const int jrow = (e8 * 2 + jt) * 16 + n15;
#pragma unroll
    for (int kc = 0; kc < 2; ++kc)
#pragma unroll
      for (int s = 0; s < 3; ++s)
        afr[jt][kc][s] =
            *(const bf16x8*)(Wsp + ((s * 256 + jrow) * 64 + kc * 32 + quad * 8));
  }

  for (int i = tid; i < HBUF / 4; i += 512) ((float*)smc)[i] = 0.f;  // zero buf 0
  if (tid < 64) idsb[tid] = inst[(rb + tid) * NSEQ];

  float cst[8];   // cells: [jt][rt] -> jt*4+rt
#pragma unroll
  for (int i = 0; i < 8; ++i) cst[i] = 0.f;

  __syncthreads();

#pragma unroll 1
  for (int t = 0; t < NSEQ; ++t) {
    const char* __restrict__ hbr = smc + (t & 1) * HBUF;
    char* __restrict__ hbw = smc + ((t & 1) ^ 1) * HBUF;
    const bool last = (t == NSEQ - 1);

    if (tid < 64 && t + 1 < NSEQ)
      idsb[((t + 1) & 1) * 64 + tid] = inst[(rb + tid) * NSEQ + t + 1];

    // es for rt=0 (consumed after rt0's MFMA block)
    float4 esc[2], esn[2];
    {
      const int v0 = idsb[(t & 1) * 64 + n15];
#pragma unroll
      for (int jt = 0; jt < 2; ++jt)
        esc[jt] = *(const float4*)(embedWi + v0 * 256 +
                                   (e8 * 8 + jt * 4 + quad) * 4);
    }

#pragma unroll
    for (int rt = 0; rt < 4; ++rt) {
      // prefetch next rt's es (hidden under this rt's MFMAs)
      if (rt < 3) {
        const int vn = idsb[(t & 1) * 64 + (rt + 1) * 16 + n15];
#pragma unroll
        for (int jt = 0; jt < 2; ++jt)
          esn[jt] = *(const float4*)(embedWi + vn * 256 +
                                     (e8 * 8 + jt * 4 + quad) * 4);
      }
      // B-frags for this rt (3 splits x 2 k-chunks)
      bf16x8 bfr[2][3];
#pragma unroll
      for (int kc = 0; kc < 2; ++kc)
#pragma unroll
        for (int s = 0; s < 3; ++s)
          bfr[kc][s] = *(const bf16x8*)(hbr + s * SPL + rt * RTG +
                                        (kc * 4 + quad) * CHK + n15 * 16);
      f32x4 C2[2];
#pragma unroll
      for (int jt = 0; jt < 2; ++jt) C2[jt] = (f32x4){0.f, 0.f, 0.f, 0.f};
#pragma unroll
      for (int jt = 0; jt < 2; ++jt) {
#pragma unroll
        for (int kc = 0; kc < 2; ++kc) {
          f32x4 acc = C2[jt];
          acc = __builtin_amdgcn_mfma_f32_16x16x32_bf16(afr[jt][kc][0], bfr[kc][2], acc, 0, 0, 0);
          acc = __builtin_amdgcn_mfma_f32_16x16x32_bf16(afr[jt][kc][2], bfr[kc][0], acc, 0, 0, 0);
          acc = __builtin_amdgcn_mfma_f32_16x16x32_bf16(afr[jt][kc][1], bfr[kc][1], acc, 0, 0, 0);
          acc = __builtin_amdgcn_mfma_f32_16x16x32_bf16(afr[jt][kc][0], bfr[kc][1], acc, 0, 0, 0);
          acc = __builtin_amdgcn_mfma_f32_16x16x32_bf16(afr[jt][kc][1], bfr[kc][0], acc, 0, 0, 0);
          acc = __builtin_amdgcn_mfma_f32_16x16x32_bf16(afr[jt][kc][0], bfr[kc][0], acc, 0, 0, 0);
          C2[jt] = acc;
        }
      }

      // epilogue for this rt: 2 cells/lane, writes to hbw (other buffer)
      float hval[2];
      unsigned short s1[2], s2[2], s3[2];
#pragma unroll
      for (int jt = 0; jt < 2; ++jt) {
        const float gi = C2[jt].x + esc[jt].x;
        const float gf = C2[jt].y + esc[jt].y;
        const float gg = C2[jt].z + esc[jt].z;
        const float go = C2[jt].w + esc[jt].w;
        const float ci = sigm(gf) * cst[jt * 4 + rt] + sigm(gi) * tanh_(gg);
        cst[jt * 4 + rt] = ci;
        const float h = sigm(go) * tanh_(ci);
        hval[jt] = h;
        float f1, f2, f3;
        s1[jt] = bfbits(h, f1);
        s2[jt] = bfbits(h - f1, f2);
        s3[jt] = bfbits(h - f1 - f2, f3);
      }
      char* base = hbw + rt * RTG + e8 * CHK + n15 * 16 + quad * 4;
      *(uint32_t*)(base + 0 * SPL) = (uint32_t)s1[0] | ((uint32_t)s1[1] << 16);
      *(uint32_t*)(base + 1 * SPL) = (uint32_t)s2[0] | ((uint32_t)s2[1] << 16);
      *(uint32_t*)(base + 2 * SPL) = (uint32_t)s3[0] | ((uint32_t)s3[1] << 16);
      if (last) {
#pragma unroll
        for (int jt = 0; jt < 2; ++jt)
          hT[(e8 * 8 + jt * 4 + quad) * NROWS + rowbase + rt * 16 + n15] = hval[jt];
      }
      esc[0] = esn[0]; esc[1] = esn[1];
    }
    __syncthreads();
  }
}

// ---------------- kernel C: heads, 4-lane team per row (bit-exact r3+) -----
__global__ __launch_bounds__(256) void k_heads(
    const int* __restrict__ canvas0, const int* __restrict__ canvas1,
    const int* __restrict__ ref,
    const float* __restrict__ Wc, const float* __restrict__ bc,
    const float* __restrict__ Ws, const float* __restrict__ bs,
    const float* __restrict__ Wl, const float* __restrict__ bl,
    const float* __restrict__ Wr1, const float* __restrict__ br1,
    const float* __restrict__ Wr2, const float* __restrict__ br2,
    const float* __restrict__ Wp, const float* __restrict__ bp,
    const float* __restrict__ hT, float* __restrict__ out) {
  const int tid = threadIdx.x;
  const int g = tid & 3;
  const int s = blockIdx.x & 1;
  const int b = (blockIdx.x >> 1) * 64 + (tid >> 2);
  const float NEG = -__builtin_inff();

  uint32_t kk0[7], kk1[7];
#pragma unroll
  for (int i = 0; i < 7; ++i) {
    uint32_t o0, o1; tf2x32(0u, 42u, 0u, (uint32_t)i, o0, o1);
    kk0[i] = o0; kk1[i] = o1;
  }

  float h[64];
#pragma unroll
  for (int u = 0; u < 64; ++u) h[u] = hT[u * NROWS + s * NB + b];

  float lgc[1], lgs[1];
  lgc[0] = (g < 3) ? (bc[g] + dot64(Wc + g * 64, h)) : NEG;
  lgs[0] = (g < 3) ? (bs[g] + dot64(Ws + g * 64, h)) : NEG;

  if (s == 0) {
    int cs0, ss0, loc0; float clp0, slp0, llp0;
    samp_team<1>(lgc, g, 3, kk0[0], kk1[0], b, cs0, clp0);
    samp_team<1>(lgs, g, 3, kk0[1], kk1[1], b, ss0, slp0);
    float lgl[7];
#pragma unroll
    for (int i = 0; i < 7; ++i) {
      const int cc = g + 4 * i;
      lgl[i] = (cc < 25) ? (bl[cc] + dot64(Wl + cc * 64, h)) : NEG;
    }
    samp_team<7>(lgl, g, 25, kk0[2], kk1[2], b, loc0, llp0);

    if (g == 0) {
      const int p0 = min(max(loc0, 0), 24);
      const int4 pt = ((const int4*)(canvas1 + b * 100))[p0];
      const bool ok0 = (loc0 >= 0) && (loc0 < 25) && (pt.x + pt.y + pt.z + pt.w >= 0);
      const float loc_r0 = ok0 ? 1.f : -1.f;
      const float col_r0 = ok0 ? ((cs0 == pt.x) ? 1.f : -1.f) : 0.f;
      out[0 * NB + b] = clp0;
      out[1 * NB + b] = slp0;
      out[2 * NB + b] = llp0;
      out[7 * NB + b] = loc_r0;
      out[8 * NB + b] = col_r0;
      out[9 * NB + b] = loc_r0;
    }
  } else {
    int cs1, ss1, ls1; float clp1, slp1, llp1;
    samp_team<1>(lgc, g, 3, kk0[3], kk1[3], b, cs1, clp1);
    samp_team<1>(lgs, g, 3, kk0[4], kk1[4], b, ss1, slp1);
    float lgp[2];
#pragma unroll
    for (int i = 0; i < 2; ++i) {
      const int cc = g + 4 * i;
      lgp[i] = bp[cc] + dot64(Wp + cc * 64, h);
    }
    samp_team<2>(lgp, g, 8, kk0[5], kk1[5], b, ls1, llp1);

    float uv8[8], w64[8], w65[8], w66[8], w67[8], wr2[8];
#pragma unroll
    for (int i = 0; i < 8; ++i) {
      const int j = g + 4 * i;
      uv8[i] = br1[j] + dot64(Wr1 + j * 68, h);
      const float* wr = Wr1 + j * 68 + 64;
      w64[i] = wr[0]; w65[i] = wr[1]; w66[i] = wr[2]; w67[i] = wr[3];
      wr2[i] = Wr2[j];
    }
    float lgA[7];
#pragma unroll
    for (int i = 0; i < 7; ++i) lgA[i] = NEG;
    const float b2 = br2[0];
#pragma unroll
    for (int p = 0; p < 25; ++p) {
      const int4 c4 = ((const int4*)(canvas0 + b * 100))[p];
      const float f0 = (float)c4.x, f1 = (float)c4.y;
      const float f2 = (float)c4.z, f3 = (float)c4.w;
      float part = 0.f;
#pragma unroll
      for (int i = 0; i < 8; ++i) {
        float hj = uv8[i];
        hj = fmaf(w64[i], f0, hj);
        hj = fmaf(w65[i], f1, hj);
        hj = fmaf(w66[i], f2, hj);
        hj = fmaf(w67[i], f3, hj);
        part = fmaf(wr2[i], fmaxf(hj, 0.f), part);
      }
      part += __shfl_xor(part, 1);
      part += __shfl_xor(part, 2);
      const float ap = b2 + part;
      if ((p & 3) == g) lgA[p >> 2] = ap;
    }
    int att_s; float alp1;
    samp_team<7>(lgA, g, 25, kk0[6], kk1[6], b, att_s, alp1);

    if (g == 0) {
      const int4 r4 = ((const int4*)(canvas0 + b * 100))[att_s];
      const int4 rr = *(const int4*)(ref + b * 4);
      const bool match = (r4.x == rr.x) && (r4.y == rr.y) &&
                         (r4.z == rr.z) && (r4.w == rr.w);
      const float att_reward = match ? 1.f : -1.f;
      const int ox = (int)((0x22001120u >> (ls1 * 4)) & 0xFu) - 1;
      const int oy = (int)((0x20200211u >> (ls1 * 4)) & 0xFu) - 1;
      const int loc1 = (r4.z + ox) * 5 + (r4.w + oy);
      const int p1 = min(max(loc1, 0), 24);
      const int4 q4 = ((const int4*)(canvas1 + b * 100))[p1];
      const bool ok1 = (loc1 >= 0) && (loc1 < 25) && (q4.x + q4.y + q4.z + q4.w >= 0);
      const float loc_r1 = ok1 ? 1.f : -1.f;
      const float col_r1 = ok1 ? ((cs1 == q4.x) ? 1.f : -1.f) : 0.f;
      out[3 * NB + b]  = clp1;
      out[4 * NB + b]  = slp1;
      out[5 * NB + b]  = llp1;
      out[6 * NB + b]  = alp1;
      out[10 * NB + b] = loc_r1;
      out[11 * NB + b] = col_r1;
      out[12 * NB + b] = loc_r1;
      out[13 * NB + b] = att_reward;
    }
  }
}

extern "C" void kernel_launch(void* const* d_in, const int* in_sizes, int n_in,
                              void* d_out, int out_size, void* d_ws, size_t ws_size,
                              hipStream_t stream) {
  const int* inst0 = (const int*)d_in[0];
  const int* inst1 = (const int*)d_in[1];
  const int* canvas0 = (const int*)d_in[2];
  const int* canvas1 = (const int*)d_in[3];
  const int* ref = (const int*)d_in[4];
  const float* embed = (const float*)d_in[5];
  const float* W_ih = (const float*)d_in[6];
  const float* W_hh = (const float*)d_in[7];
  const float* b_ih = (const float*)d_in[8];
  const float* b_hh = (const float*)d_in[9];
  const float* Wc = (const float*)d_in[10];
  const float* bc = (const float*)d_in[11];
  const float* Ws = (const float*)d_in[12];
  const float* bs = (const float*)d_in[13];
  const float* Wl = (const float*)d_in[14];
  const float* bl = (const float*)d_in[15];
  const float* Wr1 = (const float*)d_in[16];
  const float* br1 = (const float*)d_in[17];
  const float* Wr2 = (const float*)d_in[18];
  const float* br2 = (const float*)d_in[19];
  const float* Wp = (const float*)d_in[20];
  const float* bp = (const float*)d_in[21];

  float* ws = (float*)d_ws;
  float* embedWi = ws;                               // 1001*256 fp32
  unsigned short* Wsp = (unsigned short*)(ws + NV * 256);  // 3*256*64 bf16
  float* hT = ws + NV * 256 + 24576;                 // 64*32768 fp32
  float* out = (float*)d_out;

  const size_t ldsBytes = 2 * HBUF + 512;  // h dbuf (52224) + ids
  k_prep<<<NV + 192, 256, 0, stream>>>(embed, W_ih, W_hh, b_ih, b_hh, embedWi, Wsp);
  k_lstm<<<512, 512, ldsBytes, stream>>>(inst0, inst1, embedWi, Wsp, hT);
  k_heads<<<512, 256, 0, stream>>>(canvas0, canvas1, ref, Wc, bc, Ws, bs,
                                   Wl, bl, Wr1, br1, Wr2, br2, Wp, bp, hT, out);
}